// Round 1
// baseline (640.397 us; speedup 1.0000x reference)
//
#include <hip/hip_runtime.h>
#include <hip/hip_bf16.h>
#include <stdint.h>

// ---- problem constants ----
static constexpr int Bn = 8;
static constexpr int HW = 4096;     // 64*64
static constexpr int Cc = 256;
static constexpr int Gg = 32;
static constexpr int M_TOT = Bn * HW;   // 32768
static constexpr float EPSV = 1e-6f;

typedef __attribute__((ext_vector_type(8))) short bf8_t;   // 8 bf16 (4 VGPR)
typedef __attribute__((ext_vector_type(4))) float f4_t;    // mfma acc

__device__ __forceinline__ ushort f2bf(float x) {
    union { float f; uint32_t u; } v; v.f = x;
    uint32_t r = v.u + 0x7FFFu + ((v.u >> 16) & 1u);
    return (ushort)(r >> 16);
}

// ---------------- weight convert + transpose: wT[which][d][c] = bf16(w[c][d]) ----------------
__global__ void wconv_kernel(const float* __restrict__ wq, const float* __restrict__ wk,
                             const float* __restrict__ wv, const float* __restrict__ wp,
                             ushort* __restrict__ wT) {
    const float* w = (blockIdx.y == 0) ? wq : (blockIdx.y == 1) ? wk : (blockIdx.y == 2) ? wv : wp;
    int idx = blockIdx.x * 256 + threadIdx.x;        // 65536 total
    int d = idx >> 8, c = idx & 255;
    wT[blockIdx.y * 65536 + d * 256 + c] = f2bf(w[c * 256 + d]);
}

// ---------------- GroupNorm ----------------
// pass 1: per (b, slice of 256 pixels) partial sums per group
__global__ void gn_partial(const float* __restrict__ x, float* __restrict__ psum, float* __restrict__ psumsq) {
    int slice = blockIdx.x;   // 16
    int b = blockIdx.y;       // 8
    int c = threadIdx.x;      // 256
    const float* xp = x + ((size_t)b * HW + (size_t)slice * 256) * Cc + c;
    float s = 0.f, sq = 0.f;
    for (int p = 0; p < 256; ++p) { float v = xp[(size_t)p * Cc]; s += v; sq += v * v; }
    // reduce over the 8 channels of a group (adjacent lanes)
    for (int m = 1; m < 8; m <<= 1) { s += __shfl_xor(s, m); sq += __shfl_xor(sq, m); }
    if ((c & 7) == 0) {
        int g = c >> 3;
        psum[(b * Gg + g) * 16 + slice] = s;
        psumsq[(b * Gg + g) * 16 + slice] = sq;
    }
}

__global__ void gn_stats(const float* __restrict__ psum, const float* __restrict__ psumsq,
                         float* __restrict__ stats) {
    int t = threadIdx.x;  // 256 = b*32+g
    float s = 0.f, sq = 0.f;
    for (int i = 0; i < 16; ++i) { s += psum[t * 16 + i]; sq += psumsq[t * 16 + i]; }
    float mean = s * (1.0f / 32768.0f);
    float var = sq * (1.0f / 32768.0f) - mean * mean;
    stats[t * 2] = mean;
    stats[t * 2 + 1] = rsqrtf(var + EPSV);
}

// pass 2: normalize + affine, write bf16 h_
__global__ void gn_norm(const float* __restrict__ x, const float* __restrict__ stats,
                        const float* __restrict__ gs, const float* __restrict__ gb,
                        ushort* __restrict__ h) {
    size_t e = ((size_t)blockIdx.x * 256 + threadIdx.x) * 4;   // grid 8192
    int c = (int)(e & 255);
    int b = (int)(e >> 20);       // 4096*256 = 2^20 per batch
    int g = c >> 3;
    float2 st = *(const float2*)&stats[(b * Gg + g) * 2];
    float4 v = *(const float4*)&x[e];
    float4 sc = *(const float4*)&gs[c];
    float4 bi = *(const float4*)&gb[c];
    ushort4 o;
    o.x = f2bf((v.x - st.x) * st.y * sc.x + bi.x);
    o.y = f2bf((v.y - st.x) * st.y * sc.y + bi.y);
    o.z = f2bf((v.z - st.x) * st.y * sc.z + bi.z);
    o.w = f2bf((v.w - st.x) * st.y * sc.w + bi.w);
    *(ushort4*)&h[e] = o;
}

// ---------------- QKV GEMM: out = bf16((h @ w + bias) * scale) ----------------
// block: 256 thr (4 waves), each wave -> 16 rows x 256 cols. grid (M/64, 3)
__global__ __launch_bounds__(256) void qkv_gemm(const ushort* __restrict__ h, const ushort* __restrict__ wT,
                                                const float* __restrict__ bq, const float* __restrict__ bk,
                                                const float* __restrict__ bv,
                                                ushort* __restrict__ q, ushort* __restrict__ k,
                                                ushort* __restrict__ v) {
    int which = blockIdx.y;
    const ushort* w = wT + which * 65536;
    const float* bias = which == 0 ? bq : which == 1 ? bk : bv;
    ushort* out = which == 0 ? q : which == 1 ? k : v;
    float scale = which == 0 ? 0.0625f : 1.0f;   // c^-0.5 folded into q

    int lane = threadIdx.x & 63, wvi = threadIdx.x >> 6;
    int lq = lane & 15, lg = lane >> 4;
    int m0 = blockIdx.x * 64 + wvi * 16;

    bf8_t a[8];
    const ushort* arow = h + (size_t)(m0 + lq) * 256 + lg * 8;
#pragma unroll
    for (int ks = 0; ks < 8; ++ks) a[ks] = *(const bf8_t*)(arow + ks * 32);

    f4_t acc[16];
#pragma unroll
    for (int i = 0; i < 16; ++i) acc[i] = (f4_t)0.f;

    const ushort* brow = w + (size_t)lq * 256 + lg * 8;   // row nf*16+lq
#pragma unroll
    for (int nf = 0; nf < 16; ++nf) {
#pragma unroll
        for (int ks = 0; ks < 8; ++ks) {
            bf8_t bfr = *(const bf8_t*)(brow + nf * 16 * 256 + ks * 32);
            acc[nf] = __builtin_amdgcn_mfma_f32_16x16x32_bf16(a[ks], bfr, acc[nf], 0, 0, 0);
        }
    }
#pragma unroll
    for (int nf = 0; nf < 16; ++nf) {
        int col = nf * 16 + lq;
        float bsv = bias[col];
#pragma unroll
        for (int r = 0; r < 4; ++r) {
            int row = m0 + lg * 4 + r;
            out[(size_t)row * 256 + col] = f2bf((acc[nf][r] + bsv) * scale);
        }
    }
}

// ---------------- flash attention ----------------
// grid 512 (1D): batch = bid & 7 (XCD pinning), qt = bid >> 3. block 256 thr (4 waves),
// wave owns 16 q-rows. K-tile 64x256 and V^T-tile 256x64 staged in LDS (swizzled).
__global__ __launch_bounds__(256) void flash_kernel(const ushort* __restrict__ q, const ushort* __restrict__ kk,
                                                    const ushort* __restrict__ vvp, ushort* __restrict__ out) {
    __shared__ __align__(16) ushort K_lds[64 * 256];
    __shared__ __align__(16) ushort V_lds[256 * 64];
    __shared__ __align__(16) ushort P_lds[4 * 16 * 64];

    int bid = blockIdx.x;
    int batch = bid & 7, qt = bid >> 3;
    int t = threadIdx.x, lane = t & 63, wvi = t >> 6;
    int lq = lane & 15, lg = lane >> 4;
    const size_t bb = (size_t)batch * HW * Cc;

    // Q fragments in registers (B-operand layout: col = lq -> q-row, k contiguous)
    int qr = qt * 64 + wvi * 16 + lq;
    bf8_t qf[8];
    const ushort* qrow = q + bb + (size_t)qr * Cc + lg * 8;
#pragma unroll
    for (int ks = 0; ks < 8; ++ks) qf[ks] = *(const bf8_t*)(qrow + ks * 32);

    f4_t o[16];
#pragma unroll
    for (int i = 0; i < 16; ++i) o[i] = (f4_t)0.f;
    float m_i = -1e30f, l_i = 0.f;

    char* Kb = (char*)K_lds;
    char* Vb = (char*)V_lds;
    char* Pb = (char*)(P_lds + wvi * 16 * 64);

    for (int kt = 0; kt < 64; ++kt) {
        __syncthreads();
        // stage K tile (64 rows x 256 c), XOR-swizzled rows
        const ushort* ksrc = kk + bb + (size_t)kt * 64 * Cc;
        const ushort* vsrc = vvp + bb + (size_t)kt * 64 * Cc;
#pragma unroll
        for (int i = 0; i < 8; ++i) {
            int idx = i * 256 + t;
            int kr = idx >> 5, c0 = (idx & 31) * 8;
            uint4 val = *(const uint4*)(ksrc + (size_t)kr * Cc + c0);
            int ad = (kr * 512 + c0 * 2) ^ ((kr & 7) << 4);
            *(uint4*)(Kb + ad) = val;
        }
        // stage V transposed: Vt[d][kr]
#pragma unroll
        for (int i = 0; i < 8; ++i) {
            int idx = i * 256 + t;
            int kr = idx >> 5, c0 = (idx & 31) * 8;
            uint4 val = *(const uint4*)(vsrc + (size_t)kr * Cc + c0);
            ushort vals[8];
            *(uint4*)vals = val;
#pragma unroll
            for (int j = 0; j < 8; ++j) {
                int d = c0 + j;
                int ad = (d * 128 + kr * 2) ^ (((d ^ (d >> 3)) & 7) << 4);
                *(ushort*)(Vb + ad) = vals[j];
            }
        }
        __syncthreads();

        // S^T tile: mfma(K, Q): sa[mf][r] = S^T[kt*64 + mf*16 + lg*4 + r][q-row lq]
        f4_t sa[4];
#pragma unroll
        for (int mf = 0; mf < 4; ++mf) sa[mf] = (f4_t)0.f;
#pragma unroll
        for (int mf = 0; mf < 4; ++mf) {
            int krl = mf * 16 + lq;
#pragma unroll
            for (int ks = 0; ks < 8; ++ks) {
                int cc = ks * 32 + lg * 8;
                int ad = (krl * 512 + cc * 2) ^ ((krl & 7) << 4);
                bf8_t kf = *(const bf8_t*)(Kb + ad);
                sa[mf] = __builtin_amdgcn_mfma_f32_16x16x32_bf16(kf, qf[ks], sa[mf], 0, 0, 0);
            }
        }

        // online softmax (per lane: 16 scores of q-row lq)
        float tmax = -1e30f;
#pragma unroll
        for (int mf = 0; mf < 4; ++mf)
#pragma unroll
            for (int r = 0; r < 4; ++r) tmax = fmaxf(tmax, sa[mf][r]);
        tmax = fmaxf(tmax, __shfl_xor(tmax, 16));
        tmax = fmaxf(tmax, __shfl_xor(tmax, 32));
        float m_new = fmaxf(m_i, tmax);
        float tsum = 0.f;
#pragma unroll
        for (int mf = 0; mf < 4; ++mf) {
#pragma unroll
            for (int r = 0; r < 4; ++r) {
                float p = __expf(sa[mf][r] - m_new);
                sa[mf][r] = p;
                tsum += p;
            }
        }
        tsum += __shfl_xor(tsum, 16);
        tsum += __shfl_xor(tsum, 32);
        float alpha = __expf(m_i - m_new);
        l_i = l_i * alpha + tsum;
        m_i = m_new;

        // write P (bf16) to per-wave LDS: P[q=lq][k]
#pragma unroll
        for (int mf = 0; mf < 4; ++mf) {
#pragma unroll
            for (int rp = 0; rp < 2; ++rp) {
                uint32_t pk = (uint32_t)f2bf(sa[mf][rp * 2]) | ((uint32_t)f2bf(sa[mf][rp * 2 + 1]) << 16);
                int kidx = mf * 16 + lg * 4 + rp * 2;
                int ad = (lq * 128 + kidx * 2) ^ ((lq & 7) << 4);
                *(uint32_t*)(Pb + ad) = pk;
            }
        }

        // rescale O by alpha of its rows (row = lg*4 + r)
        float ar[4];
#pragma unroll
        for (int r = 0; r < 4; ++r) ar[r] = __shfl(alpha, lg * 4 + r);
#pragma unroll
        for (int nf = 0; nf < 16; ++nf)
#pragma unroll
            for (int r = 0; r < 4; ++r) o[nf][r] *= ar[r];

        // PV: o += P @ V   (A = P from LDS, B = Vt fragments)
#pragma unroll
        for (int ks2 = 0; ks2 < 2; ++ks2) {
            int k2 = ks2 * 32 + lg * 8;
            int pad = (lq * 128 + k2 * 2) ^ ((lq & 7) << 4);
            bf8_t pf = *(const bf8_t*)(Pb + pad);
#pragma unroll
            for (int nf = 0; nf < 16; ++nf) {
                int d = nf * 16 + lq;
                int vad = (d * 128 + k2 * 2) ^ (((d ^ (d >> 3)) & 7) << 4);
                bf8_t vf = *(const bf8_t*)(Vb + vad);
                o[nf] = __builtin_amdgcn_mfma_f32_16x16x32_bf16(pf, vf, o[nf], 0, 0, 0);
            }
        }
    }

    // epilogue: divide by l, store bf16
    float ir[4];
#pragma unroll
    for (int r = 0; r < 4; ++r) { float lr = __shfl(l_i, lg * 4 + r); ir[r] = 1.0f / lr; }
    size_t orow = bb + (size_t)(qt * 64 + wvi * 16) * Cc;
#pragma unroll
    for (int nf = 0; nf < 16; ++nf) {
        int col = nf * 16 + lq;
#pragma unroll
        for (int r = 0; r < 4; ++r) {
            out[orow + (size_t)(lg * 4 + r) * Cc + col] = f2bf(o[nf][r] * ir[r]);
        }
    }
}

// ---------------- proj GEMM + bias + residual (fp32 out) ----------------
__global__ __launch_bounds__(256) void proj_gemm(const ushort* __restrict__ ao, const ushort* __restrict__ wT,
                                                 const float* __restrict__ bp, const float* __restrict__ x,
                                                 float* __restrict__ outp) {
    int lane = threadIdx.x & 63, wvi = threadIdx.x >> 6;
    int lq = lane & 15, lg = lane >> 4;
    int m0 = blockIdx.x * 64 + wvi * 16;

    bf8_t a[8];
    const ushort* arow = ao + (size_t)(m0 + lq) * 256 + lg * 8;
#pragma unroll
    for (int ks = 0; ks < 8; ++ks) a[ks] = *(const bf8_t*)(arow + ks * 32);

    f4_t acc[16];
#pragma unroll
    for (int i = 0; i < 16; ++i) acc[i] = (f4_t)0.f;

    const ushort* brow = wT + (size_t)lq * 256 + lg * 8;
#pragma unroll
    for (int nf = 0; nf < 16; ++nf) {
#pragma unroll
        for (int ks = 0; ks < 8; ++ks) {
            bf8_t bfr = *(const bf8_t*)(brow + nf * 16 * 256 + ks * 32);
            acc[nf] = __builtin_amdgcn_mfma_f32_16x16x32_bf16(a[ks], bfr, acc[nf], 0, 0, 0);
        }
    }
#pragma unroll
    for (int nf = 0; nf < 16; ++nf) {
        int col = nf * 16 + lq;
        float bsv = bp[col];
#pragma unroll
        for (int r = 0; r < 4; ++r) {
            size_t idx = (size_t)(m0 + lg * 4 + r) * 256 + col;
            outp[idx] = x[idx] + acc[nf][r] + bsv;
        }
    }
}

extern "C" void kernel_launch(void* const* d_in, const int* in_sizes, int n_in,
                              void* d_out, int out_size, void* d_ws, size_t ws_size,
                              hipStream_t stream) {
    const float* x  = (const float*)d_in[0];
    const float* gs = (const float*)d_in[1];
    const float* gb = (const float*)d_in[2];
    const float* wq = (const float*)d_in[3];
    const float* bq = (const float*)d_in[4];
    const float* wk = (const float*)d_in[5];
    const float* bk = (const float*)d_in[6];
    const float* wv = (const float*)d_in[7];
    const float* bv = (const float*)d_in[8];
    const float* wp = (const float*)d_in[9];
    const float* bp = (const float*)d_in[10];
    float* out = (float*)d_out;

    char* ws = (char*)d_ws;
    ushort* wT    = (ushort*)ws;                         // 512 KB (4 x 256x256 bf16)
    float*  psum  = (float*)(ws + 512 * 1024);           // 16 KB
    float*  psumsq= (float*)(ws + 528 * 1024);           // 16 KB
    float*  stats = (float*)(ws + 544 * 1024);           // 2 KB
    ushort* h     = (ushort*)(ws + (1 << 20));           // 16 MB (later reused as attn_out)
    ushort* qb    = (ushort*)(ws + (size_t)17 * (1 << 20));
    ushort* kb    = (ushort*)(ws + (size_t)33 * (1 << 20));
    ushort* vb    = (ushort*)(ws + (size_t)49 * (1 << 20));

    wconv_kernel<<<dim3(256, 4), 256, 0, stream>>>(wq, wk, wv, wp, wT);
    gn_partial<<<dim3(16, 8), 256, 0, stream>>>(x, psum, psumsq);
    gn_stats<<<1, 256, 0, stream>>>(psum, psumsq, stats);
    gn_norm<<<8192, 256, 0, stream>>>(x, stats, gs, gb, h);
    qkv_gemm<<<dim3(512, 3), 256, 0, stream>>>(h, wT, bq, bk, bv, qb, kb, vb);
    flash_kernel<<<512, 256, 0, stream>>>(qb, kb, vb, h);
    proj_gemm<<<512, 256, 0, stream>>>(h, wT + 3 * 65536, bp, x, out);
}

// Round 2
// 456.779 us; speedup vs baseline: 1.4020x; 1.4020x over previous
//
#include <hip/hip_runtime.h>
#include <hip/hip_bf16.h>
#include <stdint.h>

// ---- problem constants ----
static constexpr int HW = 4096;     // 64*64
static constexpr int Cc = 256;
static constexpr int Gg = 32;
static constexpr float EPSV = 1e-6f;

typedef __attribute__((ext_vector_type(8))) short bf8_t;   // 8 bf16 (4 VGPR)
typedef __attribute__((ext_vector_type(4))) float f4_t;    // mfma acc

__device__ __forceinline__ ushort f2bf(float x) {
    union { float f; uint32_t u; } v; v.f = x;
    uint32_t r = v.u + 0x7FFFu + ((v.u >> 16) & 1u);
    return (ushort)(r >> 16);
}

// async global->LDS DMA, 16B per lane; lds dest must be wave-uniform base (+lane*16 by HW)
__device__ __forceinline__ void gload16(const void* g, void* l) {
    __builtin_amdgcn_global_load_lds((const __attribute__((address_space(1))) void*)g,
                                     (__attribute__((address_space(3))) void*)l, 16, 0, 0);
}

// ---------------- weight convert + transpose: wT[which][d][c] = bf16(w[c][d]) ----------------
__global__ void wconv_kernel(const float* __restrict__ wq, const float* __restrict__ wk,
                             const float* __restrict__ wv, const float* __restrict__ wp,
                             ushort* __restrict__ wT) {
    const float* w = (blockIdx.y == 0) ? wq : (blockIdx.y == 1) ? wk : (blockIdx.y == 2) ? wv : wp;
    int idx = blockIdx.x * 256 + threadIdx.x;        // 65536 total
    int d = idx >> 8, c = idx & 255;
    wT[blockIdx.y * 65536 + d * 256 + c] = f2bf(w[c * 256 + d]);
}

// ---------------- GroupNorm ----------------
__global__ void gn_partial(const float* __restrict__ x, float* __restrict__ psum, float* __restrict__ psumsq) {
    int slice = blockIdx.x;   // 16
    int b = blockIdx.y;       // 8
    int c = threadIdx.x;      // 256
    const float* xp = x + ((size_t)b * HW + (size_t)slice * 256) * Cc + c;
    float s = 0.f, sq = 0.f;
    for (int p = 0; p < 256; ++p) { float v = xp[(size_t)p * Cc]; s += v; sq += v * v; }
    for (int m = 1; m < 8; m <<= 1) { s += __shfl_xor(s, m); sq += __shfl_xor(sq, m); }
    if ((c & 7) == 0) {
        int g = c >> 3;
        psum[(b * Gg + g) * 16 + slice] = s;
        psumsq[(b * Gg + g) * 16 + slice] = sq;
    }
}

__global__ void gn_stats(const float* __restrict__ psum, const float* __restrict__ psumsq,
                         float* __restrict__ stats) {
    int t = threadIdx.x;  // 256 = b*32+g
    float s = 0.f, sq = 0.f;
    for (int i = 0; i < 16; ++i) { s += psum[t * 16 + i]; sq += psumsq[t * 16 + i]; }
    float mean = s * (1.0f / 32768.0f);
    float var = sq * (1.0f / 32768.0f) - mean * mean;
    stats[t * 2] = mean;
    stats[t * 2 + 1] = rsqrtf(var + EPSV);
}

__global__ void gn_norm(const float* __restrict__ x, const float* __restrict__ stats,
                        const float* __restrict__ gs, const float* __restrict__ gb,
                        ushort* __restrict__ h) {
    size_t e = ((size_t)blockIdx.x * 256 + threadIdx.x) * 4;   // grid 8192
    int c = (int)(e & 255);
    int b = (int)(e >> 20);
    int g = c >> 3;
    float2 st = *(const float2*)&stats[(b * Gg + g) * 2];
    float4 v = *(const float4*)&x[e];
    float4 sc = *(const float4*)&gs[c];
    float4 bi = *(const float4*)&gb[c];
    ushort4 o;
    o.x = f2bf((v.x - st.x) * st.y * sc.x + bi.x);
    o.y = f2bf((v.y - st.x) * st.y * sc.y + bi.y);
    o.z = f2bf((v.z - st.x) * st.y * sc.z + bi.z);
    o.w = f2bf((v.w - st.x) * st.y * sc.w + bi.w);
    *(ushort4*)&h[e] = o;
}

// ---------------- QKV GEMM ----------------
// which==0: q (scaled by c^-0.5), which==1: k, which==2: V TRANSPOSED -> vT[b][d][hw]
__global__ __launch_bounds__(256) void qkv_gemm(const ushort* __restrict__ h, const ushort* __restrict__ wT,
                                                const float* __restrict__ bq, const float* __restrict__ bk,
                                                const float* __restrict__ bv,
                                                ushort* __restrict__ q, ushort* __restrict__ k,
                                                ushort* __restrict__ vT) {
    int which = blockIdx.y;
    const ushort* w = wT + which * 65536;
    const float* bias = which == 0 ? bq : which == 1 ? bk : bv;
    float scale = which == 0 ? 0.0625f : 1.0f;

    int lane = threadIdx.x & 63, wvi = threadIdx.x >> 6;
    int lq = lane & 15, lg = lane >> 4;
    int m0 = blockIdx.x * 64 + wvi * 16;

    bf8_t a[8];
    const ushort* arow = h + (size_t)(m0 + lq) * 256 + lg * 8;
#pragma unroll
    for (int ks = 0; ks < 8; ++ks) a[ks] = *(const bf8_t*)(arow + ks * 32);

    f4_t acc[16];
#pragma unroll
    for (int i = 0; i < 16; ++i) acc[i] = (f4_t)0.f;

    const ushort* brow = w + (size_t)lq * 256 + lg * 8;
#pragma unroll
    for (int nf = 0; nf < 16; ++nf) {
#pragma unroll
        for (int ks = 0; ks < 8; ++ks) {
            bf8_t bfr = *(const bf8_t*)(brow + nf * 16 * 256 + ks * 32);
            acc[nf] = __builtin_amdgcn_mfma_f32_16x16x32_bf16(a[ks], bfr, acc[nf], 0, 0, 0);
        }
    }
    if (which == 2) {
        // store transposed: vT[batch][d=col][hw], 4 consecutive rows per lane (8B store)
        int bt = m0 >> 12;
        int hw0 = (m0 & 4095) + lg * 4;
#pragma unroll
        for (int nf = 0; nf < 16; ++nf) {
            int col = nf * 16 + lq;
            float bsv = bias[col];
            ushort4 pk;
            pk.x = f2bf(acc[nf][0] + bsv);
            pk.y = f2bf(acc[nf][1] + bsv);
            pk.z = f2bf(acc[nf][2] + bsv);
            pk.w = f2bf(acc[nf][3] + bsv);
            *(ushort4*)&vT[(size_t)bt * (256 * 4096) + (size_t)col * 4096 + hw0] = pk;
        }
    } else {
        ushort* out = which == 0 ? q : k;
#pragma unroll
        for (int nf = 0; nf < 16; ++nf) {
            int col = nf * 16 + lq;
            float bsv = bias[col];
#pragma unroll
            for (int r = 0; r < 4; ++r) {
                int row = m0 + lg * 4 + r;
                out[(size_t)row * 256 + col] = f2bf((acc[nf][r] + bsv) * scale);
            }
        }
    }
}

// ---------------- flash attention ----------------
// 256 blocks (batch = bid&7 for XCD pinning, qt = bid>>3, 32 q-tiles of 128 rows per batch).
// 4 waves; each wave owns 32 q-rows (2 MFMA col-tiles) so every K/V fragment feeds 2 MFMAs.
// KVBLK=64, double-buffered K (2x32KB) + Vt (2x32KB) staged via global_load_lds with
// pre-swizzled sources; per-wave P buffers (4x4KB). Dynamic LDS = 144 KB.
__global__ __launch_bounds__(256, 1) void flash_kernel(const ushort* __restrict__ q,
                                                       const ushort* __restrict__ kk,
                                                       const ushort* __restrict__ vT,
                                                       ushort* __restrict__ out) {
    extern __shared__ char smem[];
    const int t = threadIdx.x, lane = t & 63, wvi = t >> 6;
    const int lq = lane & 15, lg = lane >> 4;
    const int bid = blockIdx.x;
    const int batch = bid & 7, qt = bid >> 3;
    const size_t bb = (size_t)batch * HW * Cc;

    // Q fragments for 2 q-subtiles
    const int qbase = qt * 128 + wvi * 32;
    bf8_t qf0[8], qf1[8];
    {
        const ushort* qr0 = q + bb + (size_t)(qbase + lq) * Cc + lg * 8;
        const ushort* qr1 = qr0 + 16 * Cc;
#pragma unroll
        for (int ks = 0; ks < 8; ++ks) {
            qf0[ks] = *(const bf8_t*)(qr0 + ks * 32);
            qf1[ks] = *(const bf8_t*)(qr1 + ks * 32);
        }
    }

    f4_t o0[16], o1[16];
#pragma unroll
    for (int i = 0; i < 16; ++i) { o0[i] = (f4_t)0.f; o1[i] = (f4_t)0.f; }
    float m0 = -1e30f, l0 = 0.f, m1 = -1e30f, l1 = 0.f;

    char* Pb = smem + 131072 + wvi * 4096;   // P0 at +0 (2KB), P1 at +2048

    const ushort* ksrc_b = kk + bb;
    const ushort* vsrc_b = vT + (size_t)batch * (256 * 4096);
    const int tb = wvi * 64;

    auto stage = [&](int kt, int bufsel) {
        const ushort* ks_ = ksrc_b + (size_t)kt * 64 * 256;
        const ushort* vs_ = vsrc_b + kt * 64;
        char* kd = smem + bufsel * 32768;
        char* vd = smem + 65536 + bufsel * 32768;
        // K tile: 64 rows x 512B; LDS slot (kr, c') holds global chunk c = c' ^ (kr&7)
#pragma unroll
        for (int i = 0; i < 8; ++i) {
            int n = i * 256 + tb + lane;
            int kr = n >> 5;
            int c = (n & 31) ^ (kr & 7);
            gload16(ks_ + kr * 256 + c * 8, kd + (i * 256 + tb) * 16);
        }
        // Vt tile: 256 rows x 128B; slot (d, c') holds chunk c = c' ^ (d&7)
#pragma unroll
        for (int i = 0; i < 8; ++i) {
            int n = i * 256 + tb + lane;
            int d = n >> 3;
            int c = (n & 7) ^ (d & 7);
            gload16(vs_ + (size_t)d * HW + c * 8, vd + (i * 256 + tb) * 16);
        }
    };

    stage(0, 0);

    for (int kt = 0; kt < 64; ++kt) {
        const int cur = kt & 1;
        if (kt + 1 < 64) {
            stage(kt + 1, cur ^ 1);
            asm volatile("s_waitcnt vmcnt(16)" ::: "memory");   // current tile's 16 DMAs done
        } else {
            asm volatile("s_waitcnt vmcnt(0)" ::: "memory");
        }
        __builtin_amdgcn_s_barrier();
        __builtin_amdgcn_sched_barrier(0);

        const char* Kb = smem + cur * 32768;
        const char* Vb = smem + 65536 + cur * 32768;

        // QK^T (swapped): sa[mf][r] = S^T[k = mf*16+lg*4+r][q-col = lq]
        f4_t sa0[4], sa1[4];
#pragma unroll
        for (int mf = 0; mf < 4; ++mf) { sa0[mf] = (f4_t)0.f; sa1[mf] = (f4_t)0.f; }
#pragma unroll
        for (int ks = 0; ks < 8; ++ks) {
#pragma unroll
            for (int mf = 0; mf < 4; ++mf) {
                int kr = mf * 16 + lq;
                bf8_t kf = *(const bf8_t*)(Kb + kr * 512 + (((ks * 4 + lg) ^ (kr & 7)) * 16));
                sa0[mf] = __builtin_amdgcn_mfma_f32_16x16x32_bf16(kf, qf0[ks], sa0[mf], 0, 0, 0);
                sa1[mf] = __builtin_amdgcn_mfma_f32_16x16x32_bf16(kf, qf1[ks], sa1[mf], 0, 0, 0);
            }
        }

        // ---- online softmax, qtile0 ----
        float al0, al1;
        {
            float tmax = -1e30f;
#pragma unroll
            for (int mf = 0; mf < 4; ++mf)
#pragma unroll
                for (int r = 0; r < 4; ++r) tmax = fmaxf(tmax, sa0[mf][r]);
            tmax = fmaxf(tmax, __shfl_xor(tmax, 16));
            tmax = fmaxf(tmax, __shfl_xor(tmax, 32));
            float mn = fmaxf(m0, tmax);
            float ts = 0.f;
#pragma unroll
            for (int mf = 0; mf < 4; ++mf)
#pragma unroll
                for (int r = 0; r < 4; ++r) { float p = __expf(sa0[mf][r] - mn); sa0[mf][r] = p; ts += p; }
            ts += __shfl_xor(ts, 16);
            ts += __shfl_xor(ts, 32);
            al0 = __expf(m0 - mn); l0 = l0 * al0 + ts; m0 = mn;
#pragma unroll
            for (int mf = 0; mf < 4; ++mf)
#pragma unroll
                for (int rp = 0; rp < 2; ++rp) {
                    uint32_t pk = (uint32_t)f2bf(sa0[mf][rp * 2]) | ((uint32_t)f2bf(sa0[mf][rp * 2 + 1]) << 16);
                    int kx = mf * 16 + lg * 4 + rp * 2;
                    *(uint32_t*)(Pb + lq * 128 + (((kx >> 3) ^ (lq & 7)) * 16) + (kx & 7) * 2) = pk;
                }
        }
        // ---- online softmax, qtile1 ----
        {
            float tmax = -1e30f;
#pragma unroll
            for (int mf = 0; mf < 4; ++mf)
#pragma unroll
                for (int r = 0; r < 4; ++r) tmax = fmaxf(tmax, sa1[mf][r]);
            tmax = fmaxf(tmax, __shfl_xor(tmax, 16));
            tmax = fmaxf(tmax, __shfl_xor(tmax, 32));
            float mn = fmaxf(m1, tmax);
            float ts = 0.f;
#pragma unroll
            for (int mf = 0; mf < 4; ++mf)
#pragma unroll
                for (int r = 0; r < 4; ++r) { float p = __expf(sa1[mf][r] - mn); sa1[mf][r] = p; ts += p; }
            ts += __shfl_xor(ts, 16);
            ts += __shfl_xor(ts, 32);
            al1 = __expf(m1 - mn); l1 = l1 * al1 + ts; m1 = mn;
#pragma unroll
            for (int mf = 0; mf < 4; ++mf)
#pragma unroll
                for (int rp = 0; rp < 2; ++rp) {
                    uint32_t pk = (uint32_t)f2bf(sa1[mf][rp * 2]) | ((uint32_t)f2bf(sa1[mf][rp * 2 + 1]) << 16);
                    int kx = mf * 16 + lg * 4 + rp * 2;
                    *(uint32_t*)(Pb + 2048 + lq * 128 + (((kx >> 3) ^ (lq & 7)) * 16) + (kx & 7) * 2) = pk;
                }
        }

        // rescale O by per-row alpha
        float a0r[4], a1r[4];
#pragma unroll
        for (int r = 0; r < 4; ++r) {
            a0r[r] = __shfl(al0, lg * 4 + r);
            a1r[r] = __shfl(al1, lg * 4 + r);
        }
#pragma unroll
        for (int nf = 0; nf < 16; ++nf)
#pragma unroll
            for (int r = 0; r < 4; ++r) { o0[nf][r] *= a0r[r]; o1[nf][r] *= a1r[r]; }

        // PV: o += P @ V  (A = P from per-wave LDS, B = Vt fragments, shared across qtiles)
#pragma unroll
        for (int ks2 = 0; ks2 < 2; ++ks2) {
            int chunk = ks2 * 4 + lg;
            bf8_t pf0 = *(const bf8_t*)(Pb + lq * 128 + ((chunk ^ (lq & 7)) * 16));
            bf8_t pf1 = *(const bf8_t*)(Pb + 2048 + lq * 128 + ((chunk ^ (lq & 7)) * 16));
#pragma unroll
            for (int nf = 0; nf < 16; ++nf) {
                int d = nf * 16 + lq;
                bf8_t vf = *(const bf8_t*)(Vb + d * 128 + ((chunk ^ (d & 7)) * 16));
                o0[nf] = __builtin_amdgcn_mfma_f32_16x16x32_bf16(pf0, vf, o0[nf], 0, 0, 0);
                o1[nf] = __builtin_amdgcn_mfma_f32_16x16x32_bf16(pf1, vf, o1[nf], 0, 0, 0);
            }
        }
        __syncthreads();   // all reads of cur done before it is restaged next iter
    }

    // epilogue
    float i0[4], i1[4];
#pragma unroll
    for (int r = 0; r < 4; ++r) {
        i0[r] = 1.0f / __shfl(l0, lg * 4 + r);
        i1[r] = 1.0f / __shfl(l1, lg * 4 + r);
    }
    size_t obase = bb + (size_t)qbase * Cc;
#pragma unroll
    for (int nf = 0; nf < 16; ++nf) {
        int col = nf * 16 + lq;
#pragma unroll
        for (int r = 0; r < 4; ++r) {
            out[obase + (size_t)(lg * 4 + r) * Cc + col] = f2bf(o0[nf][r] * i0[r]);
            out[obase + (size_t)(16 + lg * 4 + r) * Cc + col] = f2bf(o1[nf][r] * i1[r]);
        }
    }
}

// ---------------- proj GEMM + bias + residual (fp32 out) ----------------
__global__ __launch_bounds__(256) void proj_gemm(const ushort* __restrict__ ao, const ushort* __restrict__ wT,
                                                 const float* __restrict__ bp, const float* __restrict__ x,
                                                 float* __restrict__ outp) {
    int lane = threadIdx.x & 63, wvi = threadIdx.x >> 6;
    int lq = lane & 15, lg = lane >> 4;
    int m0 = blockIdx.x * 64 + wvi * 16;

    bf8_t a[8];
    const ushort* arow = ao + (size_t)(m0 + lq) * 256 + lg * 8;
#pragma unroll
    for (int ks = 0; ks < 8; ++ks) a[ks] = *(const bf8_t*)(arow + ks * 32);

    f4_t acc[16];
#pragma unroll
    for (int i = 0; i < 16; ++i) acc[i] = (f4_t)0.f;

    const ushort* brow = wT + (size_t)lq * 256 + lg * 8;
#pragma unroll
    for (int nf = 0; nf < 16; ++nf) {
#pragma unroll
        for (int ks = 0; ks < 8; ++ks) {
            bf8_t bfr = *(const bf8_t*)(brow + nf * 16 * 256 + ks * 32);
            acc[nf] = __builtin_amdgcn_mfma_f32_16x16x32_bf16(a[ks], bfr, acc[nf], 0, 0, 0);
        }
    }
#pragma unroll
    for (int nf = 0; nf < 16; ++nf) {
        int col = nf * 16 + lq;
        float bsv = bp[col];
#pragma unroll
        for (int r = 0; r < 4; ++r) {
            size_t idx = (size_t)(m0 + lg * 4 + r) * 256 + col;
            outp[idx] = x[idx] + acc[nf][r] + bsv;
        }
    }
}

extern "C" void kernel_launch(void* const* d_in, const int* in_sizes, int n_in,
                              void* d_out, int out_size, void* d_ws, size_t ws_size,
                              hipStream_t stream) {
    const float* x  = (const float*)d_in[0];
    const float* gs = (const float*)d_in[1];
    const float* gb = (const float*)d_in[2];
    const float* wq = (const float*)d_in[3];
    const float* bq = (const float*)d_in[4];
    const float* wk = (const float*)d_in[5];
    const float* bk = (const float*)d_in[6];
    const float* wv = (const float*)d_in[7];
    const float* bv = (const float*)d_in[8];
    const float* wp = (const float*)d_in[9];
    const float* bp = (const float*)d_in[10];
    float* out = (float*)d_out;

    char* ws = (char*)d_ws;
    ushort* wT    = (ushort*)ws;                         // 512 KB
    float*  psum  = (float*)(ws + 512 * 1024);
    float*  psumsq= (float*)(ws + 528 * 1024);
    float*  stats = (float*)(ws + 544 * 1024);
    ushort* h     = (ushort*)(ws + (1 << 20));           // 16 MB (reused as attn out)
    ushort* qb    = (ushort*)(ws + (size_t)17 * (1 << 20));
    ushort* kb    = (ushort*)(ws + (size_t)33 * (1 << 20));
    ushort* vTb   = (ushort*)(ws + (size_t)49 * (1 << 20));   // V transposed [b][d][hw]

    wconv_kernel<<<dim3(256, 4), 256, 0, stream>>>(wq, wk, wv, wp, wT);
    gn_partial<<<dim3(16, 8), 256, 0, stream>>>(x, psum, psumsq);
    gn_stats<<<1, 256, 0, stream>>>(psum, psumsq, stats);
    gn_norm<<<8192, 256, 0, stream>>>(x, stats, gs, gb, h);
    qkv_gemm<<<dim3(512, 3), 256, 0, stream>>>(h, wT, bq, bk, bv, qb, kb, vTb);

    hipFuncSetAttribute(reinterpret_cast<const void*>(flash_kernel),
                        hipFuncAttributeMaxDynamicSharedMemorySize, 147456);
    flash_kernel<<<256, 256, 147456, stream>>>(qb, kb, vTb, h);

    proj_gemm<<<512, 256, 0, stream>>>(h, wT + 3 * 65536, bp, x, out);
}